// Round 7
// baseline (188.802 us; speedup 1.0000x reference)
//
#include <hip/hip_runtime.h>

// LangNN via 16x16x32 bf16 MFMA. B=131072, H=25, A=18.
// Round-7: one wave = 16 batch rows (MT=1), WPB=8, BLK=512.
// LDS = sFrag(26 KB: enc|decX|decH|actor) + sH(20 KB) = 47104 B -> 3 blocks/CU,
// 24 waves/CU (6/SIMD), vs round 6's 16. Enc step-0 W_ih frags are ALIASED into
// the hd half of sH (hd not live until after enc step 0; barrier + per-wave clear).
// launch_bounds(512,6) caps total regs at ~84. Activation: 7 trans/element
// (5 exp2 + 2 rcp; c-path rcps merged). Biases folded via A col k=25 == 1.0.
// C/D layout (verified r4-r6): col=lane&15, row=(lane>>4)*4+q.

#define HH 25
#define NSTEP 10
#define AOUT 18
#define WPB 8
#define BLK (WPB * 64)
#define NFRG 26   // 0..7 enc(Wih+Whh) | 8..15 decX | 16..23 decH | 24..25 actor
#define FPAD 40   // 80B row stride: 16B-aligned b128 reads, 2-way conflict (free)
#define LOG2E 1.44269504088896340736f

typedef __attribute__((ext_vector_type(8))) short short8;
typedef __attribute__((ext_vector_type(4))) float f32x4;

__device__ __forceinline__ short f2bf(float x) {   // f32 -> bf16 (RNE), init only
    unsigned u = __float_as_uint(x);
    u += 0x7fffu + ((u >> 16) & 1u);
    return (short)(u >> 16);
}
__device__ __forceinline__ unsigned cvtpk(float lo, float hi) {  // 2xf32 -> packed bf16
    unsigned r;
    asm("v_cvt_pk_bf16_f32 %0, %1, %2" : "=v"(r) : "v"(lo), "v"(hi));
    return r;
}
#if __has_builtin(__builtin_amdgcn_exp2f)
#define EXP2(x) __builtin_amdgcn_exp2f(x)
#else
#define EXP2(x) exp2f(x)
#endif
#define RCP(x) __builtin_amdgcn_rcpf(x)
#define MFMA16(a, b, c) __builtin_amdgcn_mfma_f32_16x16x32_bf16((a), (b), (c), 0, 0, 0)

__global__ __launch_bounds__(BLK, 6)
void langnn_mfma16(const float* __restrict__ state,
                   const float* __restrict__ Wih_e, const float* __restrict__ Whh_e,
                   const float* __restrict__ bih_e, const float* __restrict__ bhh_e,
                   const float* __restrict__ Wih_d, const float* __restrict__ Whh_d,
                   const float* __restrict__ bih_d, const float* __restrict__ bhh_d,
                   const float* __restrict__ Wact, const float* __restrict__ bact,
                   float* __restrict__ out, int B)
{
    __shared__ __align__(16) short sFrag[NFRG][64][8];      // 26 KB
    __shared__ __align__(16) short sH[2][WPB][16][FPAD];    // 20 KB ([0]=he, [1]=hd)

    const int tid  = threadIdx.x;
    const int lane = tid & 63;
    const int w    = tid >> 6;
    const int r    = lane & 15;    // A-row / C-col lane index
    const int g    = lane >> 4;    // k-group / C row-group

    // ---- build main B-fragment table (bias folded into k=25 row) ----
    for (int i = tid; i < NFRG * 64; i += BLK) {
        const int idx = i >> 6, l = i & 63;
        const int lj = l & 15, lg = l >> 4;
        const float *W1 = nullptr, *W2 = nullptr, *B1 = nullptr, *B2 = nullptr;
        int gt = 0, jt, jmax = HH;
        if (idx < 8)       { gt = idx >> 1;        jt = idx & 1; W1 = Wih_e; W2 = Whh_e; B1 = bih_e; B2 = bhh_e; }
        else if (idx < 16) { gt = (idx - 8) >> 1;  jt = idx & 1; W1 = Wih_d; B1 = bih_d; B2 = bhh_d; }
        else if (idx < 24) { gt = (idx - 16) >> 1; jt = idx & 1; W1 = Whh_d; }
        else               { jt = idx - 24;        W1 = Wact;    B1 = bact;  jmax = AOUT; }
        const bool actor = (idx >= 24);
        const float sc = actor ? 1.f : (gt == 2 ? 2.f * LOG2E : -LOG2E);
        const int col = jt * 16 + lj;
        const int nrow = actor ? col : gt * HH + col;
        for (int e = 0; e < 8; ++e) {
            const int k = lg * 8 + e;
            float v = 0.f;
            if (col < jmax) {
                if (k < HH) {
                    v = W1[nrow * HH + k];
                    if (W2) v += W2[nrow * HH + k];
                    v *= sc;
                } else if (k == HH && B1) {
                    v = B1[nrow];
                    if (B2) v += B2[nrow];
                    v *= sc;
                }
            }
            sFrag[idx][l][e] = f2bf(v);
        }
    }
    // ---- build enc-step-0 W_ih frags ALIASED into sH[1] (hd region, 8 KB) ----
    {
        short* W0 = &sH[1][0][0][0];
        for (int i = tid; i < 8 * 64; i += BLK) {
            const int idx = i >> 6, l = i & 63;
            const int lj = l & 15, lg = l >> 4;
            const int gt = idx >> 1, jt = idx & 1;
            const float sc = (gt == 2 ? 2.f * LOG2E : -LOG2E);
            const int col = jt * 16 + lj;
            const int nrow = gt * HH + col;
            for (int e = 0; e < 8; ++e) {
                const int k = lg * 8 + e;
                float v = 0.f;
                if (col < HH) {
                    if (k < HH)       v = Wih_e[nrow * HH + k] * sc;
                    else if (k == HH) v = (bih_e[nrow] + bhh_e[nrow]) * sc;
                }
                W0[(size_t)idx * 512 + l * 8 + e] = f2bf(v);
            }
        }
    }
    // ---- init he region: zeros, col 25 = 1.0 (bias lane) ----
    {
        int* z = (int*)&sH[0][0][0][0];
        for (int i = tid; i < WPB * 16 * (FPAD / 2); i += BLK)
            z[i] = ((i % (FPAD / 2)) == 12) ? 0x3F800000 : 0;   // shorts 24|25 -> 0|1.0
    }
    __syncthreads();

    const int b0 = (blockIdx.x * WPB + w) * 16;
    float* pe = out + (size_t)B * AOUT + (size_t)(b0 + g * 4) * HH + r;

    float ce[2][4], cd[2][4];
    #pragma unroll
    for (int jt = 0; jt < 2; ++jt)
        #pragma unroll
        for (int q = 0; q < 4; ++q) { ce[jt][q] = 0.f; cd[jt][q] = 0.f; }

    // initial A-fragments: encoder x = state; decoder h = 0 (bias lane 1.0), in regs
    short8 aE, aD;
    {
        const float* sp0 = state + (size_t)(b0 + r) * HH;
        #pragma unroll
        for (int e = 0; e < 8; ++e) {
            const int k = g * 8 + e;
            aE[e] = (k < HH) ? f2bf(sp0[k]) : (k == HH ? (short)0x3F80 : (short)0);
            aD[e] = (k == HH) ? (short)0x3F80 : (short)0;
        }
    }

    auto encCell = [&](const short (*FB)[64][8]) {
        #pragma unroll
        for (int jt = 0; jt < 2; ++jt) {
            f32x4 acc[4];
            #pragma unroll
            for (int gt = 0; gt < 4; ++gt) {
                short8 Bf = *(const short8*)&FB[gt * 2 + jt][lane][0];
                f32x4 z; z[0] = z[1] = z[2] = z[3] = 0.f;
                acc[gt] = MFMA16(aE, Bf, z);
            }
            float hv[4];
            #pragma unroll
            for (int q = 0; q < 4; ++q) {
                float Ei = EXP2(acc[0][q]);
                float Ef = EXP2(acc[1][q]);
                float Eg = EXP2(acc[2][q]);
                float Eo = EXP2(acc[3][q]);
                float Pf = 1.f + Ef;
                float Pig = (1.f + Ei) * (1.f + Eg);
                float c = fmaf(ce[jt][q], Pig, (Eg - 1.f) * Pf) * RCP(Pf * Pig);
                ce[jt][q] = c;
                float Ec = EXP2(2.f * LOG2E * c);
                float Pc = 1.f + Ec;
                hv[q] = (Pc - 2.f) * RCP(Pc * (1.f + Eo));
            }
            if (jt == 0 || r < 9) {
                float* p = pe + jt * 16;
                p[0] = hv[0]; p[HH] = hv[1]; p[2 * HH] = hv[2]; p[3 * HH] = hv[3];
                unsigned p01 = cvtpk(hv[0], hv[1]), p23 = cvtpk(hv[2], hv[3]);
                short* sp = &sH[0][w][g * 4][jt * 16 + r];
                sp[0]        = (short)p01;
                sp[FPAD]     = (short)(p01 >> 16);
                sp[2 * FPAD] = (short)p23;
                sp[3 * FPAD] = (short)(p23 >> 16);
            }
        }
        aE = *(const short8*)&sH[0][w][r][g * 8];
        pe += (size_t)B * HH;
    };

    auto decCell = [&]() {
        #pragma unroll
        for (int jt = 0; jt < 2; ++jt) {
            f32x4 acc[4];
            #pragma unroll
            for (int gt = 0; gt < 4; ++gt) {
                short8 Bx = *(const short8*)&sFrag[8 + gt * 2 + jt][lane][0];
                short8 Bh = *(const short8*)&sFrag[16 + gt * 2 + jt][lane][0];
                f32x4 z; z[0] = z[1] = z[2] = z[3] = 0.f;
                acc[gt] = MFMA16(aD, Bh, MFMA16(aE, Bx, z));
            }
            float hv[4];
            #pragma unroll
            for (int q = 0; q < 4; ++q) {
                float Ei = EXP2(acc[0][q]);
                float Ef = EXP2(acc[1][q]);
                float Eg = EXP2(acc[2][q]);
                float Eo = EXP2(acc[3][q]);
                float Pf = 1.f + Ef;
                float Pig = (1.f + Ei) * (1.f + Eg);
                float c = fmaf(cd[jt][q], Pig, (Eg - 1.f) * Pf) * RCP(Pf * Pig);
                cd[jt][q] = c;
                float Ec = EXP2(2.f * LOG2E * c);
                float Pc = 1.f + Ec;
                hv[q] = (Pc - 2.f) * RCP(Pc * (1.f + Eo));
            }
            if (jt == 0 || r < 9) {
                unsigned p01 = cvtpk(hv[0], hv[1]), p23 = cvtpk(hv[2], hv[3]);
                short* sp = &sH[1][w][g * 4][jt * 16 + r];
                sp[0]        = (short)p01;
                sp[FPAD]     = (short)(p01 >> 16);
                sp[2 * FPAD] = (short)p23;
                sp[3 * FPAD] = (short)(p23 >> 16);
            }
        }
        aD = *(const short8*)&sH[1][w][r][g * 8];
    };

    // enc step 0 reads its frags from the sH[1] alias (all waves) ...
    encCell((const short (*)[64][8])&sH[1][0][0][0]);
    __syncthreads();   // ... so barrier before hd region is reclaimed
    {   // per-wave clear of own hd region: zeros, col 25 = 1.0
        int* z = (int*)&sH[1][w][0][0];
        for (int i = lane; i < 16 * (FPAD / 2); i += 64)
            z[i] = ((i % (FPAD / 2)) == 12) ? 0x3F800000 : 0;
    }
    decCell();                          // dec step 0
    #pragma unroll 1
    for (int t = 1; t < NSTEP; ++t) {
        encCell(sFrag);                 // enc step t (combined Wih+Whh frags)
        decCell();                      // dec step t
    }

    // ---- actor head (aD holds hd(9); bias via k=25) ----
    #pragma unroll
    for (int jt = 0; jt < 2; ++jt) {
        short8 Bf = *(const short8*)&sFrag[24 + jt][lane][0];
        f32x4 z; z[0] = z[1] = z[2] = z[3] = 0.f;
        f32x4 o = MFMA16(aD, Bf, z);
        if (jt == 0 || r < 2) {
            float* p = out + (size_t)(b0 + g * 4) * AOUT + jt * 16 + r;
            p[0] = o[0]; p[AOUT] = o[1]; p[2 * AOUT] = o[2]; p[3 * AOUT] = o[3];
        }
    }
}

extern "C" void kernel_launch(void* const* d_in, const int* in_sizes, int n_in,
                              void* d_out, int out_size, void* d_ws, size_t ws_size,
                              hipStream_t stream) {
    const float* state = (const float*)d_in[0];
    const float* Wih_e = (const float*)d_in[1];
    const float* Whh_e = (const float*)d_in[2];
    const float* bih_e = (const float*)d_in[3];
    const float* bhh_e = (const float*)d_in[4];
    const float* Wih_d = (const float*)d_in[5];
    const float* Whh_d = (const float*)d_in[6];
    const float* bih_d = (const float*)d_in[7];
    const float* bhh_d = (const float*)d_in[8];
    const float* Wact  = (const float*)d_in[9];
    const float* bact  = (const float*)d_in[10];

    int B = in_sizes[0] / HH;
    int grid = B / (WPB * 16);   // 131072/128 = 1024 blocks

    hipLaunchKernelGGL(langnn_mfma16, dim3(grid), dim3(BLK), 0, stream,
                       state, Wih_e, Whh_e, bih_e, bhh_e,
                       Wih_d, Whh_d, bih_d, bhh_d, Wact, bact,
                       (float*)d_out, B);
}

// Round 8
// 95.767 us; speedup vs baseline: 1.9715x; 1.9715x over previous
//
#include <hip/hip_runtime.h>

// LangNN via 16x16x32 bf16 MFMA. B=131072, H=25, A=18.
// Round-8: round-7 structure (MT=1, WPB=8, LDS=47104B -> 3 blocks/CU,
// 24 waves/CU possible) but launch_bounds back to (512,4): round 7's (512,6)
// made the allocator collapse to 40 VGPR and spill everything (FETCH 11->367MB).
// (512,4) gave 64 VGPR / zero spill in round 6; 64 <= 85 so the LDS-limited
// 6 waves/SIMD is still reachable.
// Enc step-0 W_ih frags aliased into the hd half of sH. Biases folded via
// A col k=25 == 1.0. Activation: 5 exp2 + 2 rcp per element.
// C/D layout (verified r4-r6): col=lane&15, row=(lane>>4)*4+q.

#define HH 25
#define NSTEP 10
#define AOUT 18
#define WPB 8
#define BLK (WPB * 64)
#define NFRG 26   // 0..7 enc(Wih+Whh) | 8..15 decX | 16..23 decH | 24..25 actor
#define FPAD 40   // 80B row stride: 16B-aligned b128 reads, 2-way conflict (free)
#define LOG2E 1.44269504088896340736f

typedef __attribute__((ext_vector_type(8))) short short8;
typedef __attribute__((ext_vector_type(4))) float f32x4;

__device__ __forceinline__ short f2bf(float x) {   // f32 -> bf16 (RNE), init only
    unsigned u = __float_as_uint(x);
    u += 0x7fffu + ((u >> 16) & 1u);
    return (short)(u >> 16);
}
__device__ __forceinline__ unsigned cvtpk(float lo, float hi) {  // 2xf32 -> packed bf16
    unsigned r;
    asm("v_cvt_pk_bf16_f32 %0, %1, %2" : "=v"(r) : "v"(lo), "v"(hi));
    return r;
}
#if __has_builtin(__builtin_amdgcn_exp2f)
#define EXP2(x) __builtin_amdgcn_exp2f(x)
#else
#define EXP2(x) exp2f(x)
#endif
#define RCP(x) __builtin_amdgcn_rcpf(x)
#define MFMA16(a, b, c) __builtin_amdgcn_mfma_f32_16x16x32_bf16((a), (b), (c), 0, 0, 0)

__global__ __launch_bounds__(BLK, 4)
void langnn_mfma16(const float* __restrict__ state,
                   const float* __restrict__ Wih_e, const float* __restrict__ Whh_e,
                   const float* __restrict__ bih_e, const float* __restrict__ bhh_e,
                   const float* __restrict__ Wih_d, const float* __restrict__ Whh_d,
                   const float* __restrict__ bih_d, const float* __restrict__ bhh_d,
                   const float* __restrict__ Wact, const float* __restrict__ bact,
                   float* __restrict__ out, int B)
{
    __shared__ __align__(16) short sFrag[NFRG][64][8];      // 26 KB
    __shared__ __align__(16) short sH[2][WPB][16][FPAD];    // 20 KB ([0]=he, [1]=hd)

    const int tid  = threadIdx.x;
    const int lane = tid & 63;
    const int w    = tid >> 6;
    const int r    = lane & 15;    // A-row / C-col lane index
    const int g    = lane >> 4;    // k-group / C row-group

    // ---- build main B-fragment table (bias folded into k=25 row) ----
    for (int i = tid; i < NFRG * 64; i += BLK) {
        const int idx = i >> 6, l = i & 63;
        const int lj = l & 15, lg = l >> 4;
        const float *W1 = nullptr, *W2 = nullptr, *B1 = nullptr, *B2 = nullptr;
        int gt = 0, jt, jmax = HH;
        if (idx < 8)       { gt = idx >> 1;        jt = idx & 1; W1 = Wih_e; W2 = Whh_e; B1 = bih_e; B2 = bhh_e; }
        else if (idx < 16) { gt = (idx - 8) >> 1;  jt = idx & 1; W1 = Wih_d; B1 = bih_d; B2 = bhh_d; }
        else if (idx < 24) { gt = (idx - 16) >> 1; jt = idx & 1; W1 = Whh_d; }
        else               { jt = idx - 24;        W1 = Wact;    B1 = bact;  jmax = AOUT; }
        const bool actor = (idx >= 24);
        const float sc = actor ? 1.f : (gt == 2 ? 2.f * LOG2E : -LOG2E);
        const int col = jt * 16 + lj;
        const int nrow = actor ? col : gt * HH + col;
        for (int e = 0; e < 8; ++e) {
            const int k = lg * 8 + e;
            float v = 0.f;
            if (col < jmax) {
                if (k < HH) {
                    v = W1[nrow * HH + k];
                    if (W2) v += W2[nrow * HH + k];
                    v *= sc;
                } else if (k == HH && B1) {
                    v = B1[nrow];
                    if (B2) v += B2[nrow];
                    v *= sc;
                }
            }
            sFrag[idx][l][e] = f2bf(v);
        }
    }
    // ---- build enc-step-0 W_ih frags ALIASED into sH[1] (hd region, 8 KB) ----
    {
        short* W0 = &sH[1][0][0][0];
        for (int i = tid; i < 8 * 64; i += BLK) {
            const int idx = i >> 6, l = i & 63;
            const int lj = l & 15, lg = l >> 4;
            const int gt = idx >> 1, jt = idx & 1;
            const float sc = (gt == 2 ? 2.f * LOG2E : -LOG2E);
            const int col = jt * 16 + lj;
            const int nrow = gt * HH + col;
            for (int e = 0; e < 8; ++e) {
                const int k = lg * 8 + e;
                float v = 0.f;
                if (col < HH) {
                    if (k < HH)       v = Wih_e[nrow * HH + k] * sc;
                    else if (k == HH) v = (bih_e[nrow] + bhh_e[nrow]) * sc;
                }
                W0[(size_t)idx * 512 + l * 8 + e] = f2bf(v);
            }
        }
    }
    // ---- init he region: zeros, col 25 = 1.0 (bias lane) ----
    {
        int* z = (int*)&sH[0][0][0][0];
        for (int i = tid; i < WPB * 16 * (FPAD / 2); i += BLK)
            z[i] = ((i % (FPAD / 2)) == 12) ? 0x3F800000 : 0;   // shorts 24|25 -> 0|1.0
    }
    __syncthreads();

    const int b0 = (blockIdx.x * WPB + w) * 16;
    float* pe = out + (size_t)B * AOUT + (size_t)(b0 + g * 4) * HH + r;

    float ce[2][4], cd[2][4];
    #pragma unroll
    for (int jt = 0; jt < 2; ++jt)
        #pragma unroll
        for (int q = 0; q < 4; ++q) { ce[jt][q] = 0.f; cd[jt][q] = 0.f; }

    // initial A-fragments: encoder x = state; decoder h = 0 (bias lane 1.0), in regs
    short8 aE, aD;
    {
        const float* sp0 = state + (size_t)(b0 + r) * HH;
        #pragma unroll
        for (int e = 0; e < 8; ++e) {
            const int k = g * 8 + e;
            aE[e] = (k < HH) ? f2bf(sp0[k]) : (k == HH ? (short)0x3F80 : (short)0);
            aD[e] = (k == HH) ? (short)0x3F80 : (short)0;
        }
    }

    auto encCell = [&](const short (*FB)[64][8]) {
        #pragma unroll
        for (int jt = 0; jt < 2; ++jt) {
            f32x4 acc[4];
            #pragma unroll
            for (int gt = 0; gt < 4; ++gt) {
                short8 Bf = *(const short8*)&FB[gt * 2 + jt][lane][0];
                f32x4 z; z[0] = z[1] = z[2] = z[3] = 0.f;
                acc[gt] = MFMA16(aE, Bf, z);
            }
            float hv[4];
            #pragma unroll
            for (int q = 0; q < 4; ++q) {
                float Ei = EXP2(acc[0][q]);
                float Ef = EXP2(acc[1][q]);
                float Eg = EXP2(acc[2][q]);
                float Eo = EXP2(acc[3][q]);
                float Pf = 1.f + Ef;
                float Pig = (1.f + Ei) * (1.f + Eg);
                float c = fmaf(ce[jt][q], Pig, (Eg - 1.f) * Pf) * RCP(Pf * Pig);
                ce[jt][q] = c;
                float Ec = EXP2(2.f * LOG2E * c);
                float Pc = 1.f + Ec;
                hv[q] = (Pc - 2.f) * RCP(Pc * (1.f + Eo));
            }
            if (jt == 0 || r < 9) {
                float* p = pe + jt * 16;
                p[0] = hv[0]; p[HH] = hv[1]; p[2 * HH] = hv[2]; p[3 * HH] = hv[3];
                unsigned p01 = cvtpk(hv[0], hv[1]), p23 = cvtpk(hv[2], hv[3]);
                short* sp = &sH[0][w][g * 4][jt * 16 + r];
                sp[0]        = (short)p01;
                sp[FPAD]     = (short)(p01 >> 16);
                sp[2 * FPAD] = (short)p23;
                sp[3 * FPAD] = (short)(p23 >> 16);
            }
        }
        aE = *(const short8*)&sH[0][w][r][g * 8];
        pe += (size_t)B * HH;
    };

    auto decCell = [&]() {
        #pragma unroll
        for (int jt = 0; jt < 2; ++jt) {
            f32x4 acc[4];
            #pragma unroll
            for (int gt = 0; gt < 4; ++gt) {
                short8 Bx = *(const short8*)&sFrag[8 + gt * 2 + jt][lane][0];
                short8 Bh = *(const short8*)&sFrag[16 + gt * 2 + jt][lane][0];
                f32x4 z; z[0] = z[1] = z[2] = z[3] = 0.f;
                acc[gt] = MFMA16(aD, Bh, MFMA16(aE, Bx, z));
            }
            float hv[4];
            #pragma unroll
            for (int q = 0; q < 4; ++q) {
                float Ei = EXP2(acc[0][q]);
                float Ef = EXP2(acc[1][q]);
                float Eg = EXP2(acc[2][q]);
                float Eo = EXP2(acc[3][q]);
                float Pf = 1.f + Ef;
                float Pig = (1.f + Ei) * (1.f + Eg);
                float c = fmaf(cd[jt][q], Pig, (Eg - 1.f) * Pf) * RCP(Pf * Pig);
                cd[jt][q] = c;
                float Ec = EXP2(2.f * LOG2E * c);
                float Pc = 1.f + Ec;
                hv[q] = (Pc - 2.f) * RCP(Pc * (1.f + Eo));
            }
            if (jt == 0 || r < 9) {
                unsigned p01 = cvtpk(hv[0], hv[1]), p23 = cvtpk(hv[2], hv[3]);
                short* sp = &sH[1][w][g * 4][jt * 16 + r];
                sp[0]        = (short)p01;
                sp[FPAD]     = (short)(p01 >> 16);
                sp[2 * FPAD] = (short)p23;
                sp[3 * FPAD] = (short)(p23 >> 16);
            }
        }
        aD = *(const short8*)&sH[1][w][r][g * 8];
    };

    // enc step 0 reads its frags from the sH[1] alias (all waves) ...
    encCell((const short (*)[64][8])&sH[1][0][0][0]);
    __syncthreads();   // ... so barrier before hd region is reclaimed
    {   // per-wave clear of own hd region: zeros, col 25 = 1.0
        int* z = (int*)&sH[1][w][0][0];
        for (int i = lane; i < 16 * (FPAD / 2); i += 64)
            z[i] = ((i % (FPAD / 2)) == 12) ? 0x3F800000 : 0;
    }
    decCell();                          // dec step 0
    #pragma unroll 1
    for (int t = 1; t < NSTEP; ++t) {
        encCell(sFrag);                 // enc step t (combined Wih+Whh frags)
        decCell();                      // dec step t
    }

    // ---- actor head (aD holds hd(9); bias via k=25) ----
    #pragma unroll
    for (int jt = 0; jt < 2; ++jt) {
        short8 Bf = *(const short8*)&sFrag[24 + jt][lane][0];
        f32x4 z; z[0] = z[1] = z[2] = z[3] = 0.f;
        f32x4 o = MFMA16(aD, Bf, z);
        if (jt == 0 || r < 2) {
            float* p = out + (size_t)(b0 + g * 4) * AOUT + jt * 16 + r;
            p[0] = o[0]; p[AOUT] = o[1]; p[2 * AOUT] = o[2]; p[3 * AOUT] = o[3];
        }
    }
}

extern "C" void kernel_launch(void* const* d_in, const int* in_sizes, int n_in,
                              void* d_out, int out_size, void* d_ws, size_t ws_size,
                              hipStream_t stream) {
    const float* state = (const float*)d_in[0];
    const float* Wih_e = (const float*)d_in[1];
    const float* Whh_e = (const float*)d_in[2];
    const float* bih_e = (const float*)d_in[3];
    const float* bhh_e = (const float*)d_in[4];
    const float* Wih_d = (const float*)d_in[5];
    const float* Whh_d = (const float*)d_in[6];
    const float* bih_d = (const float*)d_in[7];
    const float* bhh_d = (const float*)d_in[8];
    const float* Wact  = (const float*)d_in[9];
    const float* bact  = (const float*)d_in[10];

    int B = in_sizes[0] / HH;
    int grid = B / (WPB * 16);   // 131072/128 = 1024 blocks

    hipLaunchKernelGGL(langnn_mfma16, dim3(grid), dim3(BLK), 0, stream,
                       state, Wih_e, Whh_e, bih_e, bhh_e,
                       Wih_d, Whh_d, bih_d, bhh_d, Wact, bact,
                       (float*)d_out, B);
}